// Round 11
// baseline (828.453 us; speedup 1.0000x reference)
//
#include <hip/hip_runtime.h>

#define D 128
#define HEADS 8
#define CH 16
#define NEG 0.2f
#define LNEPS 1e-5f

typedef __attribute__((ext_vector_type(8))) short bf16x8;
typedef __attribute__((ext_vector_type(4))) float f32x4;

#define MFMA(a, b, c) __builtin_amdgcn_mfma_f32_16x16x32_bf16(a, b, c, 0, 0, 0)

__device__ __forceinline__ short f2bf(float f) {
    unsigned u = __builtin_bit_cast(unsigned, f);
    unsigned r = (u + 0x7fffu + ((u >> 16) & 1u)) >> 16;
    return (short)r;
}
__device__ __forceinline__ float bflo(unsigned u) {
    return __builtin_bit_cast(float, u << 16);
}
__device__ __forceinline__ float bfhi(unsigned u) {
    return __builtin_bit_cast(float, u & 0xffff0000u);
}
__device__ __forceinline__ bf16x8 pack8(f32x4 lo, f32x4 hi) {
    bf16x8 r;
    r[0] = f2bf(lo[0]); r[1] = f2bf(lo[1]); r[2] = f2bf(lo[2]); r[3] = f2bf(lo[3]);
    r[4] = f2bf(hi[0]); r[5] = f2bf(hi[1]); r[6] = f2bf(hi[2]); r[7] = f2bf(hi[3]);
    return r;
}

// ---- K0: convert all weight matrices to bf16 + dst histogram (merged) ----
__global__ void prep_kernel(const float* __restrict__ wl, const float* __restrict__ wr,
                            const float* __restrict__ we, const float* __restrict__ fc,
                            const float* __restrict__ pj, short* __restrict__ out,
                            const int* __restrict__ dst, int* __restrict__ counts,
                            int nE) {
    int idx = blockIdx.x * 256 + threadIdx.x;
    if (idx < 180224) {
        float v;
        if (idx < 16384) v = wl[idx];
        else if (idx < 32768) v = wr[idx - 16384];
        else if (idx < 49152) v = we[idx - 32768];
        else if (idx < 114688) v = fc[idx - 49152];
        else v = pj[idx - 114688];
        out[idx] = f2bf(v);
    }
    if (idx < nE) atomicAdd(&counts[dst[idx]], 1);
}

// ---- K1: LayerNorm1 -> bf16 ----
__global__ void ln_kernel(const float* __restrict__ x, const float* __restrict__ w,
                          short* __restrict__ h, int n) {
    int row = blockIdx.x * 4 + (threadIdx.x >> 6);
    if (row >= n) return;
    int l = threadIdx.x & 63;
    long base = (long)row * D;
    float a = x[base + l], b = x[base + l + 64];
    float s = a + b, ss = a * a + b * b;
    #pragma unroll
    for (int m = 1; m < 64; m <<= 1) { s += __shfl_xor(s, m); ss += __shfl_xor(ss, m); }
    float mu = s * (1.0f / 128.0f);
    float var = ss * (1.0f / 128.0f) - mu * mu;
    float rstd = rsqrtf(var + LNEPS);
    h[base + l]      = f2bf((a - mu) * rstd * w[l]);
    h[base + l + 64] = f2bf((b - mu) * rstd * w[l + 64]);
}

// ---- K2: xl = h@Wl^T + bl ; xr = h@Wr^T + br  -> bf16 outputs ----
__global__ __launch_bounds__(256) void node_lin_kernel(
        const short* __restrict__ h, const short* __restrict__ wl, const short* __restrict__ wr,
        const float* __restrict__ bl, const float* __restrict__ br,
        short* __restrict__ xl, short* __restrict__ xr, int n) {
    int wave = threadIdx.x >> 6, l = threadIdx.x & 63;
    int rbase = blockIdx.x * 64 + wave * 16;
    int g = l >> 4, c = l & 15;
    f32x4 acc[16];
    #pragma unroll
    for (int t = 0; t < 16; t++) acc[t] = (f32x4){0.f, 0.f, 0.f, 0.f};
    int arow = rbase + c;
    #pragma unroll
    for (int kk = 0; kk < 4; kk++) {
        int k0 = kk * 32 + g * 8;
        bf16x8 af = {};
        if (arow < n) af = *(const bf16x8*)(h + (long)arow * D + k0);
        #pragma unroll
        for (int t = 0; t < 16; t++) {
            const short* w = (t < 8) ? wl : wr;
            int col = (t & 7) * 16 + c;
            bf16x8 bf = *(const bf16x8*)(w + col * D + k0);
            acc[t] = MFMA(af, bf, acc[t]);
        }
    }
    #pragma unroll
    for (int t = 0; t < 16; t++) {
        int col = (t & 7) * 16 + c;
        short* out = (t < 8) ? xl : xr;
        float bias = (t < 8) ? bl[col] : br[col];
        #pragma unroll
        for (int r = 0; r < 4; r++) {
            int row = rbase + g * 4 + r;
            if (row < n) out[(long)row * D + col] = f2bf(acc[t][r] + bias);
        }
    }
}

// ---- CSR build: 3-phase multi-block scan / place ----
__global__ void scan1_kernel(const int* __restrict__ counts, int* __restrict__ offsets,
                             int* __restrict__ blocksum, int n) {
    __shared__ int sd[1024];
    int tid = threadIdx.x;
    int gid = blockIdx.x * 1024 + tid;
    int v = (gid < n) ? counts[gid] : 0;
    sd[tid] = v;
    __syncthreads();
    int acc = v;
    #pragma unroll
    for (int off = 1; off < 1024; off <<= 1) {
        int t = (tid >= off) ? sd[tid - off] : 0;
        __syncthreads();
        acc += t;
        sd[tid] = acc;
        __syncthreads();
    }
    if (gid < n) offsets[gid] = acc - v;
    if (tid == 1023) blocksum[blockIdx.x] = acc;
}

__global__ void scan2_kernel(int* __restrict__ blocksum, int nb) {
    __shared__ int sd[256];
    int tid = threadIdx.x;
    int v = (tid < nb) ? blocksum[tid] : 0;
    sd[tid] = v;
    __syncthreads();
    int acc = v;
    #pragma unroll
    for (int off = 1; off < 256; off <<= 1) {
        int t = (tid >= off) ? sd[tid - off] : 0;
        __syncthreads();
        acc += t;
        sd[tid] = acc;
        __syncthreads();
    }
    if (tid < nb) blocksum[tid] = acc - v;
}

__global__ void scan3_kernel(int* __restrict__ offsets, const int* __restrict__ blocksum,
                             int* __restrict__ cursor, int n) {
    int gid = blockIdx.x * 256 + threadIdx.x;
    if (gid < n) {
        int o = offsets[gid] + blocksum[gid >> 10];
        offsets[gid] = o;
        cursor[gid] = o;
    }
}

// place: assign CSR slot; emit slot->(src, dst, edge) permutation arrays
__global__ void place_kernel(const int* __restrict__ src, const int* __restrict__ dst,
                             int* __restrict__ cursor, int* __restrict__ src_perm,
                             int* __restrict__ dst_perm, int* __restrict__ eid_perm,
                             int nE) {
    int e = blockIdx.x * 256 + threadIdx.x;
    if (e < nE) {
        int d = dst[e];
        int pos = atomicAdd(&cursor[d], 1);
        src_perm[pos] = src[e];
        dst_perm[pos] = d;
        eid_perm[pos] = e;
    }
}

// ---- K3: persistent pipelined edge kernel, CSR order, fragment-ordered LDS ----
// Gathers use uint4 (16B) loads: g-pairs share an address (HW broadcast), so
// gather instr count (and TA line-touch work) is halved vs uint2.
__global__ __launch_bounds__(256) void edge_kernel(
        const float* __restrict__ ea, const short* __restrict__ we,
        const int* __restrict__ src_perm, const int* __restrict__ dst_perm,
        const int* __restrict__ eid_perm,
        const short* __restrict__ xl, const short* __restrict__ xr,
        const float* __restrict__ att, float* __restrict__ num_perm,
        int nE, int ntiles, int nwaves) {
    __shared__ short wlds[16384];   // 32 KB = 2048 x 16B fragment slots
    int tid = threadIdx.x;

    // stage we -> LDS in fragment order: dest16 = ((t*4+kk)*16+el)*4+g
    #pragma unroll
    for (int q = 0; q < 8; q++) {
        int d16 = tid * 8 + q;               // 0..2047
        int gq = d16 & 3, elq = (d16 >> 2) & 15, kkq = (d16 >> 6) & 3, tq = d16 >> 8;
        bf16x8 v = *(const bf16x8*)(we + (tq * 16 + elq) * D + kkq * 32 + gq * 8);
        *(bf16x8*)((char*)wlds + d16 * 16) = v;
    }
    __syncthreads();

    int wave = tid >> 6, l = tid & 63;
    int el = l & 15, g = l >> 4;
    int gh = (g >> 1) * 8;    // short offset of this lane's 16B half-pair
    int sel = g & 1;          // which half of the uint4 this lane owns
    long ti = (long)blockIdx.x * 4 + wave;
    if (ti >= ntiles) return;

    // loop-invariant att slice in regs
    f32x4 av[8];
    #pragma unroll
    for (int t = 0; t < 8; t++) av[t] = *(const f32x4*)(att + t * CH + g * 4);

    // prologue: idx triple + ea for first tile
    int sp, dp;
    f32x4 ear[8];
    {
        long p0 = ti * 16 + el;
        long pc = (p0 < nE) ? p0 : (nE - 1);
        sp = src_perm[pc]; dp = dst_perm[pc];
        long ep = eid_perm[pc];
        const float* p = ea + ep * D + g * 8;
        ear[0] = *(const f32x4*)(p);       ear[1] = *(const f32x4*)(p + 4);
        ear[2] = *(const f32x4*)(p + 32);  ear[3] = *(const f32x4*)(p + 36);
        ear[4] = *(const f32x4*)(p + 64);  ear[5] = *(const f32x4*)(p + 68);
        ear[6] = *(const f32x4*)(p + 96);  ear[7] = *(const f32x4*)(p + 100);
    }

    for (; ti < ntiles; ti += nwaves) {
        long pcur = ti * 16 + el;
        bool valid = pcur < nE;
        int sc = sp, dc = dp;

        // gathers for current tile: 16B per lane, g-pairs coalesce to one line
        uint4 gl4[8], gr4[8];
        #pragma unroll
        for (int t = 0; t < 8; t++) {
            gl4[t] = *(const uint4*)(xl + (long)sc * D + t * CH + gh);
            gr4[t] = *(const uint4*)(xr + (long)dc * D + t * CH + gh);
        }

        // prefetch next tile's idx triple
        long tin = ti + nwaves;
        long tcl = (tin < ntiles) ? tin : ti;
        long epn;
        {
            long pn = tcl * 16 + el;
            long pc = (pn < nE) ? pn : (nE - 1);
            sp = src_perm[pc]; dp = dst_perm[pc];
            epn = eid_perm[pc];
        }

        // pack current ea (waits on loads issued last iteration)
        bf16x8 b0 = pack8(ear[0], ear[1]);
        bf16x8 b1 = pack8(ear[2], ear[3]);
        bf16x8 b2 = pack8(ear[4], ear[5]);
        bf16x8 b3 = pack8(ear[6], ear[7]);

        // prefetch next tile's ea
        {
            const float* p = ea + epn * D + g * 8;
            ear[0] = *(const f32x4*)(p);       ear[1] = *(const f32x4*)(p + 4);
            ear[2] = *(const f32x4*)(p + 32);  ear[3] = *(const f32x4*)(p + 36);
            ear[4] = *(const f32x4*)(p + 64);  ear[5] = *(const f32x4*)(p + 68);
            ear[6] = *(const f32x4*)(p + 96);  ear[7] = *(const f32x4*)(p + 100);
        }

        // MFMA: afrag from LDS, contiguous 1KB per instr (conflict-free)
        f32x4 acc[8];
        #pragma unroll
        for (int t = 0; t < 8; t++) acc[t] = (f32x4){0.f, 0.f, 0.f, 0.f};
        #pragma unroll
        for (int kk = 0; kk < 4; kk++) {
            bf16x8 bb = (kk == 0) ? b0 : (kk == 1) ? b1 : (kk == 2) ? b2 : b3;
            #pragma unroll
            for (int t = 0; t < 8; t++) {
                int off = ((t * 4 + kk) << 10) + (el << 6) + (g << 4);
                bf16x8 af = *(const bf16x8*)((char*)wlds + off);
                acc[t] = MFMA(af, bb, acc[t]);
            }
        }

        // epilogue: z = leaky(acc + xl + xr); att-dot; reduce over g; exp; store
        float logit[8];
        #pragma unroll
        for (int t = 0; t < 8; t++) {
            unsigned lx = sel ? gl4[t].z : gl4[t].x;
            unsigned ly = sel ? gl4[t].w : gl4[t].y;
            unsigned rx = sel ? gr4[t].z : gr4[t].x;
            unsigned ry = sel ? gr4[t].w : gr4[t].y;
            float v0 = acc[t][0] + bflo(lx) + bflo(rx);
            float v1 = acc[t][1] + bfhi(lx) + bfhi(rx);
            float v2 = acc[t][2] + bflo(ly) + bflo(ry);
            float v3 = acc[t][3] + bfhi(ly) + bfhi(ry);
            v0 = v0 > 0.f ? v0 : NEG * v0;
            v1 = v1 > 0.f ? v1 : NEG * v1;
            v2 = v2 > 0.f ? v2 : NEG * v2;
            v3 = v3 > 0.f ? v3 : NEG * v3;
            float lg = v0 * av[t][0];
            lg = fmaf(v1, av[t][1], lg);
            lg = fmaf(v2, av[t][2], lg);
            lg = fmaf(v3, av[t][3], lg);
            lg += __shfl_xor(lg, 16);
            lg += __shfl_xor(lg, 32);
            logit[t] = lg;
        }
        if (g == 0 && valid) {
            float4 o0 = make_float4(__expf(logit[0]), __expf(logit[1]),
                                    __expf(logit[2]), __expf(logit[3]));
            float4 o1 = make_float4(__expf(logit[4]), __expf(logit[5]),
                                    __expf(logit[6]), __expf(logit[7]));
            *(float4*)(num_perm + pcur * HEADS) = o0;
            *(float4*)(num_perm + pcur * HEADS + 4) = o1;
        }
    }
}

// ---- K4: per-node aggregation (contiguous CSR, 4x unrolled) + LN2 fused ----
__global__ __launch_bounds__(256) void aggregate_kernel(
        const int* __restrict__ src_perm, const int* __restrict__ offsets,
        const int* __restrict__ counts, const float* __restrict__ num_perm,
        const short* __restrict__ xl, const float* __restrict__ x,
        const float* __restrict__ ab, const float* __restrict__ w2,
        float* __restrict__ x_mid, short* __restrict__ h2, int n) {
    int node = blockIdx.x * 4 + (threadIdx.x >> 6);
    if (node >= n) return;
    int l = threadIdx.x & 63;
    int h = l >> 3;                 // head of cols 2l, 2l+1
    int start = offsets[node], cnt = counts[node];
    float a0 = 0.f, a1 = 0.f, den = 0.f;
    int i = 0;
    for (; i + 4 <= cnt; i += 4) {
        int s0 = src_perm[start + i],     s1 = src_perm[start + i + 1];
        int s2 = src_perm[start + i + 2], s3 = src_perm[start + i + 3];
        float n0 = num_perm[(long)(start + i) * HEADS + h];
        float n1 = num_perm[(long)(start + i + 1) * HEADS + h];
        float n2 = num_perm[(long)(start + i + 2) * HEADS + h];
        float n3 = num_perm[(long)(start + i + 3) * HEADS + h];
        unsigned u0 = *(const unsigned*)(xl + (long)s0 * D + 2 * l);
        unsigned u1 = *(const unsigned*)(xl + (long)s1 * D + 2 * l);
        unsigned u2 = *(const unsigned*)(xl + (long)s2 * D + 2 * l);
        unsigned u3 = *(const unsigned*)(xl + (long)s3 * D + 2 * l);
        a0 = fmaf(bflo(u0), n0, a0); a1 = fmaf(bfhi(u0), n0, a1);
        a0 = fmaf(bflo(u1), n1, a0); a1 = fmaf(bfhi(u1), n1, a1);
        a0 = fmaf(bflo(u2), n2, a0); a1 = fmaf(bfhi(u2), n2, a1);
        a0 = fmaf(bflo(u3), n3, a0); a1 = fmaf(bfhi(u3), n3, a1);
        den += n0 + n1 + n2 + n3;
    }
    for (; i < cnt; i++) {
        float nm = num_perm[(long)(start + i) * HEADS + h];
        int s = src_perm[start + i];
        unsigned u = *(const unsigned*)(xl + (long)s * D + 2 * l);
        a0 = fmaf(bflo(u), nm, a0);
        a1 = fmaf(bfhi(u), nm, a1);
        den += nm;
    }
    float rden = cnt > 0 ? 1.f / den : 0.f;
    a0 *= rden; a1 *= rden;
    long base = (long)node * D;
    float2 xv = *(const float2*)(x + base + 2 * l);
    float2 abv = *(const float2*)(ab + 2 * l);
    float xm0 = xv.x + a0 + abv.x;
    float xm1 = xv.y + a1 + abv.y;
    *(float2*)(x_mid + base + 2 * l) = make_float2(xm0, xm1);
    float s_ = xm0 + xm1, ss = xm0 * xm0 + xm1 * xm1;
    #pragma unroll
    for (int m = 1; m < 64; m <<= 1) { s_ += __shfl_xor(s_, m); ss += __shfl_xor(ss, m); }
    float mu = s_ * (1.0f / 128.0f);
    float var = ss * (1.0f / 128.0f) - mu * mu;
    float rstd = rsqrtf(var + LNEPS);
    float2 wv = *(const float2*)(w2 + 2 * l);
    h2[base + 2 * l]     = f2bf((xm0 - mu) * rstd * wv.x);
    h2[base + 2 * l + 1] = f2bf((xm1 - mu) * rstd * wv.y);
}

// ---- K6: fused MLP, 128 thr / 2 waves / 32 rows; t in wave-private LDS ----
__global__ __launch_bounds__(128) void fcproj_kernel(
        const short* __restrict__ h2, const short* __restrict__ wfc,
        const short* __restrict__ wpj, const float* __restrict__ x_mid,
        float* __restrict__ out, int n) {
    __shared__ char tl[32768];   // 16KB per wave
    int wave = threadIdx.x >> 6, l = threadIdx.x & 63;
    int rbase = blockIdx.x * 32 + wave * 16;
    int g = l >> 4, c = l & 15;
    int arow = rbase + c;
    char* tw = tl + wave * 16384;

    // fc phase: two col-halves of 256
    #pragma unroll
    for (int half = 0; half < 2; half++) {
        f32x4 acc[16];
        #pragma unroll
        for (int t = 0; t < 16; t++) acc[t] = (f32x4){0.f, 0.f, 0.f, 0.f};
        #pragma unroll
        for (int kk = 0; kk < 4; kk++) {
            int k0 = kk * 32 + g * 8;
            bf16x8 af = {};
            if (arow < n) af = *(const bf16x8*)(h2 + (long)arow * D + k0);
            #pragma unroll
            for (int t = 0; t < 16; t++) {
                int col = half * 256 + t * 16 + c;
                bf16x8 bf = *(const bf16x8*)(wfc + (long)col * D + k0);
                acc[t] = MFMA(af, bf, acc[t]);
            }
        }
        #pragma unroll
        for (int t = 0; t < 16; t++) {
            int col = half * 256 + t * 16 + c;
            int kk_p = col >> 5, g_p = (col >> 3) & 3, e_p = col & 7;
            #pragma unroll
            for (int r = 0; r < 4; r++) {
                int rr = g * 4 + r;
                float v = acc[t][r];
                int addr = ((kk_p * 16 + rr) * 4 + g_p) * 16 + e_p * 2;
                *(short*)(tw + addr) = f2bf(v > 0.f ? v : 0.f);
            }
        }
    }

    // proj phase: K=512 from wave-private LDS (contiguous reads)
    f32x4 pacc[8];
    #pragma unroll
    for (int t = 0; t < 8; t++) pacc[t] = (f32x4){0.f, 0.f, 0.f, 0.f};
    #pragma unroll
    for (int kk = 0; kk < 16; kk++) {
        int k0 = kk * 32 + g * 8;
        int addr = ((kk * 16 + c) * 4 + g) * 16;
        bf16x8 af = *(const bf16x8*)(tw + addr);
        #pragma unroll
        for (int t = 0; t < 8; t++) {
            bf16x8 bf = *(const bf16x8*)(wpj + (long)(t * 16 + c) * 512 + k0);
            pacc[t] = MFMA(af, bf, pacc[t]);
        }
    }
    #pragma unroll
    for (int t = 0; t < 8; t++) {
        int col = t * 16 + c;
        #pragma unroll
        for (int r = 0; r < 4; r++) {
            int row = rbase + g * 4 + r;
            if (row < n) out[(long)row * D + col] = x_mid[(long)row * D + col] + pacc[t][r];
        }
    }
}

extern "C" void kernel_launch(void* const* d_in, const int* in_sizes, int n_in,
                              void* d_out, int out_size, void* d_ws, size_t ws_size,
                              hipStream_t stream) {
    const float* x    = (const float*)d_in[0];
    const int*   eidx = (const int*)d_in[1];
    const float* ea   = (const float*)d_in[2];
    const float* ln1w = (const float*)d_in[3];
    const float* wl   = (const float*)d_in[4];
    const float* bl   = (const float*)d_in[5];
    const float* wr   = (const float*)d_in[6];
    const float* br   = (const float*)d_in[7];
    const float* we   = (const float*)d_in[8];
    const float* att  = (const float*)d_in[9];
    const float* ab   = (const float*)d_in[10];
    const float* ln2w = (const float*)d_in[11];
    const float* wfc  = (const float*)d_in[12];
    const float* wpj  = (const float*)d_in[13];
    int N = in_sizes[0] / D;
    int E = in_sizes[1] / 2;
    const int* srcp = eidx;
    const int* dstp = eidx + E;

    char* ws = (char*)d_ws;
    size_t NB2 = (size_t)N * D * 2;       // bf16 node matrix
    size_t NB4 = (size_t)N * D * 4;       // fp32 node matrix
    size_t E84 = (size_t)E * HEADS * 4;   // num_perm
    size_t o = 0;
    short* xl_bf   = (short*)(ws + o); o += NB2;
    short* xr_bf   = (short*)(ws + o); o += NB2;
    float* numperm = (float*)(ws + o); o += E84;
    float* xmid    = (float*)(ws + o); o += NB4;
    short* hbuf    = (short*)(ws + o); o += NB2;
    short* wbf     = (short*)(ws + o); o += 180224 * 2;
    int* counts    = (int*)(ws + o);   o += (size_t)N * 4;
    int* offsets   = (int*)(ws + o);   o += (size_t)N * 4;
    int* cursor    = (int*)(ws + o);   o += (size_t)N * 4;
    int* src_perm  = (int*)(ws + o);   o += (size_t)E * 4;
    int* dst_perm  = (int*)(ws + o);   o += (size_t)E * 4;
    int* eid_perm  = (int*)(ws + o);   o += (size_t)E * 4;
    int* blocksum  = (int*)(ws + o);   o += 256 * 4;

    int nb = (N + 1023) / 1024;
    int ntiles = (E + 15) / 16;
    int egrid = 1280;                 // 5 blocks/CU (32KB LDS each)
    int nwaves = egrid * 4;
    int prep_grid = (E > 180224 ? E : 180224);
    prep_grid = (prep_grid + 255) / 256;

    hipMemsetAsync(counts, 0, (size_t)N * 4, stream);

    prep_kernel<<<prep_grid, 256, 0, stream>>>(wl, wr, we, wfc, wpj, wbf,
                                               dstp, counts, E);
    ln_kernel<<<(N + 3) / 4, 256, 0, stream>>>(x, ln1w, hbuf, N);
    node_lin_kernel<<<(N + 63) / 64, 256, 0, stream>>>(hbuf, wbf, wbf + 16384,
                                                       bl, br, xl_bf, xr_bf, N);
    scan1_kernel<<<nb, 1024, 0, stream>>>(counts, offsets, blocksum, N);
    scan2_kernel<<<1, 256, 0, stream>>>(blocksum, nb);
    scan3_kernel<<<(N + 255) / 256, 256, 0, stream>>>(offsets, blocksum, cursor, N);
    place_kernel<<<(E + 255) / 256, 256, 0, stream>>>(srcp, dstp, cursor, src_perm,
                                                      dst_perm, eid_perm, E);
    edge_kernel<<<egrid, 256, 0, stream>>>(ea, wbf + 32768, src_perm, dst_perm,
                                           eid_perm, xl_bf, xr_bf, att,
                                           numperm, E, ntiles, nwaves);
    aggregate_kernel<<<(N + 3) / 4, 256, 0, stream>>>(src_perm, offsets, counts,
                                                      numperm, xl_bf, x, ab, ln2w,
                                                      xmid, hbuf, N);
    fcproj_kernel<<<(N + 31) / 32, 128, 0, stream>>>(hbuf, wbf + 49152,
                                                     wbf + 114688, xmid,
                                                     (float*)d_out, N);
}

// Round 12
// 517.328 us; speedup vs baseline: 1.6014x; 1.6014x over previous
//
#include <hip/hip_runtime.h>

#define D 128
#define HEADS 8
#define CH 16
#define NEG 0.2f
#define LNEPS 1e-5f

typedef __attribute__((ext_vector_type(8))) short bf16x8;
typedef __attribute__((ext_vector_type(4))) float f32x4;

#define MFMA(a, b, c) __builtin_amdgcn_mfma_f32_16x16x32_bf16(a, b, c, 0, 0, 0)

__device__ __forceinline__ short f2bf(float f) {
    unsigned u = __builtin_bit_cast(unsigned, f);
    unsigned r = (u + 0x7fffu + ((u >> 16) & 1u)) >> 16;
    return (short)r;
}
__device__ __forceinline__ float bflo(unsigned u) {
    return __builtin_bit_cast(float, u << 16);
}
__device__ __forceinline__ float bfhi(unsigned u) {
    return __builtin_bit_cast(float, u & 0xffff0000u);
}
__device__ __forceinline__ bf16x8 pack8(f32x4 lo, f32x4 hi) {
    bf16x8 r;
    r[0] = f2bf(lo[0]); r[1] = f2bf(lo[1]); r[2] = f2bf(lo[2]); r[3] = f2bf(lo[3]);
    r[4] = f2bf(hi[0]); r[5] = f2bf(hi[1]); r[6] = f2bf(hi[2]); r[7] = f2bf(hi[3]);
    return r;
}

// ---- K0: convert all weight matrices to bf16 + dst histogram (merged) ----
__global__ void prep_kernel(const float* __restrict__ wl, const float* __restrict__ wr,
                            const float* __restrict__ we, const float* __restrict__ fc,
                            const float* __restrict__ pj, short* __restrict__ out,
                            const int* __restrict__ dst, int* __restrict__ counts,
                            int nE) {
    int idx = blockIdx.x * 256 + threadIdx.x;
    if (idx < 180224) {
        float v;
        if (idx < 16384) v = wl[idx];
        else if (idx < 32768) v = wr[idx - 16384];
        else if (idx < 49152) v = we[idx - 32768];
        else if (idx < 114688) v = fc[idx - 49152];
        else v = pj[idx - 114688];
        out[idx] = f2bf(v);
    }
    if (idx < nE) atomicAdd(&counts[dst[idx]], 1);
}

// ---- K1: LayerNorm1 -> bf16 ----
__global__ void ln_kernel(const float* __restrict__ x, const float* __restrict__ w,
                          short* __restrict__ h, int n) {
    int row = blockIdx.x * 4 + (threadIdx.x >> 6);
    if (row >= n) return;
    int l = threadIdx.x & 63;
    long base = (long)row * D;
    float a = x[base + l], b = x[base + l + 64];
    float s = a + b, ss = a * a + b * b;
    #pragma unroll
    for (int m = 1; m < 64; m <<= 1) { s += __shfl_xor(s, m); ss += __shfl_xor(ss, m); }
    float mu = s * (1.0f / 128.0f);
    float var = ss * (1.0f / 128.0f) - mu * mu;
    float rstd = rsqrtf(var + LNEPS);
    h[base + l]      = f2bf((a - mu) * rstd * w[l]);
    h[base + l + 64] = f2bf((b - mu) * rstd * w[l + 64]);
}

// ---- K2: xl = h@Wl^T + bl ; xr = h@Wr^T + br  -> bf16 outputs ----
__global__ __launch_bounds__(256) void node_lin_kernel(
        const short* __restrict__ h, const short* __restrict__ wl, const short* __restrict__ wr,
        const float* __restrict__ bl, const float* __restrict__ br,
        short* __restrict__ xl, short* __restrict__ xr, int n) {
    int wave = threadIdx.x >> 6, l = threadIdx.x & 63;
    int rbase = blockIdx.x * 64 + wave * 16;
    int g = l >> 4, c = l & 15;
    f32x4 acc[16];
    #pragma unroll
    for (int t = 0; t < 16; t++) acc[t] = (f32x4){0.f, 0.f, 0.f, 0.f};
    int arow = rbase + c;
    #pragma unroll
    for (int kk = 0; kk < 4; kk++) {
        int k0 = kk * 32 + g * 8;
        bf16x8 af = {};
        if (arow < n) af = *(const bf16x8*)(h + (long)arow * D + k0);
        #pragma unroll
        for (int t = 0; t < 16; t++) {
            const short* w = (t < 8) ? wl : wr;
            int col = (t & 7) * 16 + c;
            bf16x8 bf = *(const bf16x8*)(w + col * D + k0);
            acc[t] = MFMA(af, bf, acc[t]);
        }
    }
    #pragma unroll
    for (int t = 0; t < 16; t++) {
        int col = (t & 7) * 16 + c;
        short* out = (t < 8) ? xl : xr;
        float bias = (t < 8) ? bl[col] : br[col];
        #pragma unroll
        for (int r = 0; r < 4; r++) {
            int row = rbase + g * 4 + r;
            if (row < n) out[(long)row * D + col] = f2bf(acc[t][r] + bias);
        }
    }
}

// ---- CSR build: 3-phase multi-block scan / place ----
__global__ void scan1_kernel(const int* __restrict__ counts, int* __restrict__ offsets,
                             int* __restrict__ blocksum, int n) {
    __shared__ int sd[1024];
    int tid = threadIdx.x;
    int gid = blockIdx.x * 1024 + tid;
    int v = (gid < n) ? counts[gid] : 0;
    sd[tid] = v;
    __syncthreads();
    int acc = v;
    #pragma unroll
    for (int off = 1; off < 1024; off <<= 1) {
        int t = (tid >= off) ? sd[tid - off] : 0;
        __syncthreads();
        acc += t;
        sd[tid] = acc;
        __syncthreads();
    }
    if (gid < n) offsets[gid] = acc - v;
    if (tid == 1023) blocksum[blockIdx.x] = acc;
}

__global__ void scan2_kernel(int* __restrict__ blocksum, int nb) {
    __shared__ int sd[256];
    int tid = threadIdx.x;
    int v = (tid < nb) ? blocksum[tid] : 0;
    sd[tid] = v;
    __syncthreads();
    int acc = v;
    #pragma unroll
    for (int off = 1; off < 256; off <<= 1) {
        int t = (tid >= off) ? sd[tid - off] : 0;
        __syncthreads();
        acc += t;
        sd[tid] = acc;
        __syncthreads();
    }
    if (tid < nb) blocksum[tid] = acc - v;
}

__global__ void scan3_kernel(int* __restrict__ offsets, const int* __restrict__ blocksum,
                             int* __restrict__ cursor, int n) {
    int gid = blockIdx.x * 256 + threadIdx.x;
    if (gid < n) {
        int o = offsets[gid] + blocksum[gid >> 10];
        offsets[gid] = o;
        cursor[gid] = o;
    }
}

// place: assign CSR slot; emit slot->(src, dst, edge) permutation arrays
__global__ void place_kernel(const int* __restrict__ src, const int* __restrict__ dst,
                             int* __restrict__ cursor, int* __restrict__ src_perm,
                             int* __restrict__ dst_perm, int* __restrict__ eid_perm,
                             int nE) {
    int e = blockIdx.x * 256 + threadIdx.x;
    if (e < nE) {
        int d = dst[e];
        int pos = atomicAdd(&cursor[d], 1);
        src_perm[pos] = src[e];
        dst_perm[pos] = d;
        eid_perm[pos] = e;
    }
}

// ---- K3: persistent pipelined edge kernel, CSR (dst-sorted) order ----
// R8 configuration (best known): we in row-major XOR-swizzled LDS, uint2
// gathers, 1-deep ea/idx prefetch pipeline, grid-stride persistent waves.
__global__ __launch_bounds__(256) void edge_kernel(
        const float* __restrict__ ea, const short* __restrict__ we,
        const int* __restrict__ src_perm, const int* __restrict__ dst_perm,
        const int* __restrict__ eid_perm,
        const short* __restrict__ xl, const short* __restrict__ xr,
        const float* __restrict__ att, float* __restrict__ num_perm,
        int nE, int ntiles, int nwaves) {
    __shared__ short wlds[16384];   // 32 KB, row stride 256B, XOR-swizzled
    int tid = threadIdx.x;

    // stage we -> LDS once per block (coalesced; same swizzle as reads)
    {
        int row = tid >> 1, half = tid & 1;
        const short* srow = we + row * D + half * 64;
        #pragma unroll
        for (int j = 0; j < 8; j++) {
            bf16x8 v = *(const bf16x8*)(srow + j * 8);
            int off = (half * 128 + j * 16) ^ ((row & 15) << 4);
            *(bf16x8*)((char*)wlds + row * 256 + off) = v;
        }
    }
    __syncthreads();

    int wave = tid >> 6, l = tid & 63;
    int el = l & 15, g = l >> 4;
    long ti = (long)blockIdx.x * 4 + wave;
    if (ti >= ntiles) return;

    // prologue: idx triple + ea for first tile
    int sp, dp;
    f32x4 ear[8];
    {
        long p0 = ti * 16 + el;
        long pc = (p0 < nE) ? p0 : (nE - 1);
        sp = src_perm[pc]; dp = dst_perm[pc];
        long ep = eid_perm[pc];
        const float* p = ea + ep * D + g * 8;
        ear[0] = *(const f32x4*)(p);       ear[1] = *(const f32x4*)(p + 4);
        ear[2] = *(const f32x4*)(p + 32);  ear[3] = *(const f32x4*)(p + 36);
        ear[4] = *(const f32x4*)(p + 64);  ear[5] = *(const f32x4*)(p + 68);
        ear[6] = *(const f32x4*)(p + 96);  ear[7] = *(const f32x4*)(p + 100);
    }

    for (; ti < ntiles; ti += nwaves) {
        long pcur = ti * 16 + el;
        bool valid = pcur < nE;
        int sc = sp, dc = dp;

        // gathers for current tile (idx arrived during previous iteration)
        uint2 gl[8], gr[8];
        #pragma unroll
        for (int t = 0; t < 8; t++) {
            gl[t] = *(const uint2*)(xl + (long)sc * D + t * CH + g * 4);
            gr[t] = *(const uint2*)(xr + (long)dc * D + t * CH + g * 4);
        }

        // prefetch next tile's idx triple
        long tin = ti + nwaves;
        long tcl = (tin < ntiles) ? tin : ti;
        long epn;
        {
            long pn = tcl * 16 + el;
            long pc = (pn < nE) ? pn : (nE - 1);
            sp = src_perm[pc]; dp = dst_perm[pc];
            epn = eid_perm[pc];
        }

        // pack current ea (waits on loads issued last iteration)
        bf16x8 b0 = pack8(ear[0], ear[1]);
        bf16x8 b1 = pack8(ear[2], ear[3]);
        bf16x8 b2 = pack8(ear[4], ear[5]);
        bf16x8 b3 = pack8(ear[6], ear[7]);

        // prefetch next tile's ea
        {
            const float* p = ea + epn * D + g * 8;
            ear[0] = *(const f32x4*)(p);       ear[1] = *(const f32x4*)(p + 4);
            ear[2] = *(const f32x4*)(p + 32);  ear[3] = *(const f32x4*)(p + 36);
            ear[4] = *(const f32x4*)(p + 64);  ear[5] = *(const f32x4*)(p + 68);
            ear[6] = *(const f32x4*)(p + 96);  ear[7] = *(const f32x4*)(p + 100);
        }

        // MFMA: afrag from LDS (swizzled), no TA traffic
        f32x4 acc[8];
        #pragma unroll
        for (int t = 0; t < 8; t++) acc[t] = (f32x4){0.f, 0.f, 0.f, 0.f};
        #pragma unroll
        for (int kk = 0; kk < 4; kk++) {
            bf16x8 bb = (kk == 0) ? b0 : (kk == 1) ? b1 : (kk == 2) ? b2 : b3;
            #pragma unroll
            for (int t = 0; t < 8; t++) {
                int row = t * CH + el;
                int off = row * 256 + ((kk * 64 + g * 16) ^ ((row & 15) << 4));
                bf16x8 af = *(const bf16x8*)((char*)wlds + off);
                acc[t] = MFMA(af, bb, acc[t]);
            }
        }

        // epilogue: z = leaky(acc + xl + xr); att-dot; reduce over g; exp; store
        float logit[8];
        #pragma unroll
        for (int t = 0; t < 8; t++) {
            f32x4 av = *(const f32x4*)(att + t * CH + g * 4);
            float v0 = acc[t][0] + bflo(gl[t].x) + bflo(gr[t].x);
            float v1 = acc[t][1] + bfhi(gl[t].x) + bfhi(gr[t].x);
            float v2 = acc[t][2] + bflo(gl[t].y) + bflo(gr[t].y);
            float v3 = acc[t][3] + bfhi(gl[t].y) + bfhi(gr[t].y);
            v0 = v0 > 0.f ? v0 : NEG * v0;
            v1 = v1 > 0.f ? v1 : NEG * v1;
            v2 = v2 > 0.f ? v2 : NEG * v2;
            v3 = v3 > 0.f ? v3 : NEG * v3;
            float lg = v0 * av[0];
            lg = fmaf(v1, av[1], lg);
            lg = fmaf(v2, av[2], lg);
            lg = fmaf(v3, av[3], lg);
            lg += __shfl_xor(lg, 16);
            lg += __shfl_xor(lg, 32);
            logit[t] = lg;
        }
        if (g == 0 && valid) {
            float4 o0 = make_float4(__expf(logit[0]), __expf(logit[1]),
                                    __expf(logit[2]), __expf(logit[3]));
            float4 o1 = make_float4(__expf(logit[4]), __expf(logit[5]),
                                    __expf(logit[6]), __expf(logit[7]));
            *(float4*)(num_perm + pcur * HEADS) = o0;
            *(float4*)(num_perm + pcur * HEADS + 4) = o1;
        }
    }
}

// ---- K4: per-node aggregation (contiguous CSR, 4x unrolled) + LN2 fused ----
__global__ __launch_bounds__(256) void aggregate_kernel(
        const int* __restrict__ src_perm, const int* __restrict__ offsets,
        const int* __restrict__ counts, const float* __restrict__ num_perm,
        const short* __restrict__ xl, const float* __restrict__ x,
        const float* __restrict__ ab, const float* __restrict__ w2,
        float* __restrict__ x_mid, short* __restrict__ h2, int n) {
    int node = blockIdx.x * 4 + (threadIdx.x >> 6);
    if (node >= n) return;
    int l = threadIdx.x & 63;
    int h = l >> 3;                 // head of cols 2l, 2l+1
    int start = offsets[node], cnt = counts[node];
    float a0 = 0.f, a1 = 0.f, den = 0.f;
    int i = 0;
    for (; i + 4 <= cnt; i += 4) {
        int s0 = src_perm[start + i],     s1 = src_perm[start + i + 1];
        int s2 = src_perm[start + i + 2], s3 = src_perm[start + i + 3];
        float n0 = num_perm[(long)(start + i) * HEADS + h];
        float n1 = num_perm[(long)(start + i + 1) * HEADS + h];
        float n2 = num_perm[(long)(start + i + 2) * HEADS + h];
        float n3 = num_perm[(long)(start + i + 3) * HEADS + h];
        unsigned u0 = *(const unsigned*)(xl + (long)s0 * D + 2 * l);
        unsigned u1 = *(const unsigned*)(xl + (long)s1 * D + 2 * l);
        unsigned u2 = *(const unsigned*)(xl + (long)s2 * D + 2 * l);
        unsigned u3 = *(const unsigned*)(xl + (long)s3 * D + 2 * l);
        a0 = fmaf(bflo(u0), n0, a0); a1 = fmaf(bfhi(u0), n0, a1);
        a0 = fmaf(bflo(u1), n1, a0); a1 = fmaf(bfhi(u1), n1, a1);
        a0 = fmaf(bflo(u2), n2, a0); a1 = fmaf(bfhi(u2), n2, a1);
        a0 = fmaf(bflo(u3), n3, a0); a1 = fmaf(bfhi(u3), n3, a1);
        den += n0 + n1 + n2 + n3;
    }
    for (; i < cnt; i++) {
        float nm = num_perm[(long)(start + i) * HEADS + h];
        int s = src_perm[start + i];
        unsigned u = *(const unsigned*)(xl + (long)s * D + 2 * l);
        a0 = fmaf(bflo(u), nm, a0);
        a1 = fmaf(bfhi(u), nm, a1);
        den += nm;
    }
    float rden = cnt > 0 ? 1.f / den : 0.f;
    a0 *= rden; a1 *= rden;
    long base = (long)node * D;
    float2 xv = *(const float2*)(x + base + 2 * l);
    float2 abv = *(const float2*)(ab + 2 * l);
    float xm0 = xv.x + a0 + abv.x;
    float xm1 = xv.y + a1 + abv.y;
    *(float2*)(x_mid + base + 2 * l) = make_float2(xm0, xm1);
    float s_ = xm0 + xm1, ss = xm0 * xm0 + xm1 * xm1;
    #pragma unroll
    for (int m = 1; m < 64; m <<= 1) { s_ += __shfl_xor(s_, m); ss += __shfl_xor(ss, m); }
    float mu = s_ * (1.0f / 128.0f);
    float var = ss * (1.0f / 128.0f) - mu * mu;
    float rstd = rsqrtf(var + LNEPS);
    float2 wv = *(const float2*)(w2 + 2 * l);
    h2[base + 2 * l]     = f2bf((xm0 - mu) * rstd * wv.x);
    h2[base + 2 * l + 1] = f2bf((xm1 - mu) * rstd * wv.y);
}

// ---- K6: fused MLP: t = relu(h2@fc^T) in LDS; out = x_mid + t@proj^T ----
// R8 configuration: 256 thr / 4 waves / 64 rows, 64KB LDS, one barrier.
__global__ __launch_bounds__(256) void fcproj_kernel(
        const short* __restrict__ h2, const short* __restrict__ wfc,
        const short* __restrict__ wpj, const float* __restrict__ x_mid,
        float* __restrict__ out, int n) {
    __shared__ char tl[65536];   // [64 rows][512 cols] bf16, XOR-swizzled
    int wave = threadIdx.x >> 6, l = threadIdx.x & 63;
    int rbase = blockIdx.x * 64 + wave * 16;
    int g = l >> 4, c = l & 15;
    int arow = rbase + c;

    // fc phase: two col-halves of 256
    #pragma unroll
    for (int half = 0; half < 2; half++) {
        f32x4 acc[16];
        #pragma unroll
        for (int t = 0; t < 16; t++) acc[t] = (f32x4){0.f, 0.f, 0.f, 0.f};
        #pragma unroll
        for (int kk = 0; kk < 4; kk++) {
            int k0 = kk * 32 + g * 8;
            bf16x8 af = {};
            if (arow < n) af = *(const bf16x8*)(h2 + (long)arow * D + k0);
            #pragma unroll
            for (int t = 0; t < 16; t++) {
                int col = half * 256 + t * 16 + c;
                bf16x8 bf = *(const bf16x8*)(wfc + (long)col * D + k0);
                acc[t] = MFMA(af, bf, acc[t]);
            }
        }
        #pragma unroll
        for (int t = 0; t < 16; t++) {
            int col = half * 256 + t * 16 + c;
            #pragma unroll
            for (int r = 0; r < 4; r++) {
                int lr = wave * 16 + g * 4 + r;
                float v = acc[t][r];
                int addr = lr * 1024 + ((2 * col) ^ ((lr & 7) << 4));
                *(short*)(tl + addr) = f2bf(v > 0.f ? v : 0.f);
            }
        }
    }
    __syncthreads();

    // proj phase: K=512 from LDS (wave-local rows), B from global (L1)
    f32x4 pacc[8];
    #pragma unroll
    for (int t = 0; t < 8; t++) pacc[t] = (f32x4){0.f, 0.f, 0.f, 0.f};
    int lr = wave * 16 + c;
    #pragma unroll
    for (int kk = 0; kk < 16; kk++) {
        int k0 = kk * 32 + g * 8;
        int addr = lr * 1024 + ((2 * k0) ^ ((lr & 7) << 4));
        bf16x8 af = *(const bf16x8*)(tl + addr);
        #pragma unroll
        for (int t = 0; t < 8; t++) {
            bf16x8 bf = *(const bf16x8*)(wpj + (long)(t * 16 + c) * 512 + k0);
            pacc[t] = MFMA(af, bf, pacc[t]);
        }
    }
    #pragma unroll
    for (int t = 0; t < 8; t++) {
        int col = t * 16 + c;
        #pragma unroll
        for (int r = 0; r < 4; r++) {
            int row = rbase + g * 4 + r;
            if (row < n) out[(long)row * D + col] = x_mid[(long)row * D + col] + pacc[t][r];
        }
    }
}

extern "C" void kernel_launch(void* const* d_in, const int* in_sizes, int n_in,
                              void* d_out, int out_size, void* d_ws, size_t ws_size,
                              hipStream_t stream) {
    const float* x    = (const float*)d_in[0];
    const int*   eidx = (const int*)d_in[1];
    const float* ea   = (const float*)d_in[2];
    const float* ln1w = (const float*)d_in[3];
    const float* wl   = (const float*)d_in[4];
    const float* bl   = (const float*)d_in[5];
    const float* wr   = (const float*)d_in[6];
    const float* br   = (const float*)d_in[7];
    const float* we   = (const float*)d_in[8];
    const float* att  = (const float*)d_in[9];
    const float* ab   = (const float*)d_in[10];
    const float* ln2w = (const float*)d_in[11];
    const float* wfc  = (const float*)d_in[12];
    const float* wpj  = (const float*)d_in[13];
    int N = in_sizes[0] / D;
    int E = in_sizes[1] / 2;
    const int* srcp = eidx;
    const int* dstp = eidx + E;

    char* ws = (char*)d_ws;
    size_t NB2 = (size_t)N * D * 2;       // bf16 node matrix
    size_t NB4 = (size_t)N * D * 4;       // fp32 node matrix
    size_t E84 = (size_t)E * HEADS * 4;   // num_perm
    size_t o = 0;
    short* xl_bf   = (short*)(ws + o); o += NB2;
    short* xr_bf   = (short*)(ws + o); o += NB2;
    float* numperm = (float*)(ws + o); o += E84;
    float* xmid    = (float*)(ws + o); o += NB4;
    short* hbuf    = (short*)(ws + o); o += NB2;
    short* wbf     = (short*)(ws + o); o += 180224 * 2;
    int* counts    = (int*)(ws + o);   o += (size_t)N * 4;
    int* offsets   = (int*)(ws + o);   o += (size_t)N * 4;
    int* cursor    = (int*)(ws + o);   o += (size_t)N * 4;
    int* src_perm  = (int*)(ws + o);   o += (size_t)E * 4;
    int* dst_perm  = (int*)(ws + o);   o += (size_t)E * 4;
    int* eid_perm  = (int*)(ws + o);   o += (size_t)E * 4;
    int* blocksum  = (int*)(ws + o);   o += 256 * 4;

    int nb = (N + 1023) / 1024;
    int ntiles = (E + 15) / 16;
    int egrid = 1280;                 // persistent: 5 blocks/CU cap by LDS
    int nwaves = egrid * 4;
    int prep_grid = (E > 180224 ? E : 180224);
    prep_grid = (prep_grid + 255) / 256;

    hipMemsetAsync(counts, 0, (size_t)N * 4, stream);

    prep_kernel<<<prep_grid, 256, 0, stream>>>(wl, wr, we, wfc, wpj, wbf,
                                               dstp, counts, E);
    ln_kernel<<<(N + 3) / 4, 256, 0, stream>>>(x, ln1w, hbuf, N);
    node_lin_kernel<<<(N + 63) / 64, 256, 0, stream>>>(hbuf, wbf, wbf + 16384,
                                                       bl, br, xl_bf, xr_bf, N);
    scan1_kernel<<<nb, 1024, 0, stream>>>(counts, offsets, blocksum, N);
    scan2_kernel<<<1, 256, 0, stream>>>(blocksum, nb);
    scan3_kernel<<<(N + 255) / 256, 256, 0, stream>>>(offsets, blocksum, cursor, N);
    place_kernel<<<(E + 255) / 256, 256, 0, stream>>>(srcp, dstp, cursor, src_perm,
                                                      dst_perm, eid_perm, E);
    edge_kernel<<<egrid, 256, 0, stream>>>(ea, wbf + 32768, src_perm, dst_perm,
                                           eid_perm, xl_bf, xr_bf, att,
                                           numperm, E, ntiles, nwaves);
    aggregate_kernel<<<(N + 3) / 4, 256, 0, stream>>>(src_perm, offsets, counts,
                                                      numperm, xl_bf, x, ab, ln2w,
                                                      xmid, hbuf, N);
    fcproj_kernel<<<(N + 63) / 64, 256, 0, stream>>>(hbuf, wbf + 49152,
                                                     wbf + 114688, xmid,
                                                     (float*)d_out, N);
}